// Round 1
// baseline (205.582 us; speedup 1.0000x reference)
//
#include <hip/hip_runtime.h>
#include <hip/hip_bf16.h>

typedef __bf16 bf16x8 __attribute__((ext_vector_type(8)));
typedef __bf16 bf16x4 __attribute__((ext_vector_type(4)));
typedef float f32x4 __attribute__((ext_vector_type(4)));

#define SLEN 2048
#define NHEADS 16
#define HDIM 64

// ---------------- cast hidden fp32 -> bf16 ----------------
__global__ __launch_bounds__(256) void cast_f32_bf16(const float* __restrict__ in,
                                                     __bf16* __restrict__ out, int n4) {
    int i = blockIdx.x * 256 + threadIdx.x;
    if (i < n4) {
        float4 v = reinterpret_cast<const float4*>(in)[i];
        bf16x4 o = { (__bf16)v.x, (__bf16)v.y, (__bf16)v.z, (__bf16)v.w };
        reinterpret_cast<bf16x4*>(out)[i] = o;
    }
}

// ---------------- transpose + cast: W[K][N] fp32 -> Wt[N][K] bf16 ----------------
__global__ __launch_bounds__(256) void transpose_cast(const float* __restrict__ W,
                                                      __bf16* __restrict__ Wt,
                                                      int K, int N) {
    __shared__ float tile[32][33];
    int n0 = blockIdx.x * 32, k0 = blockIdx.y * 32;
    int tx = threadIdx.x, ty = threadIdx.y;
    #pragma unroll
    for (int i = ty; i < 32; i += 8)
        tile[i][tx] = W[(size_t)(k0 + i) * N + n0 + tx];
    __syncthreads();
    #pragma unroll
    for (int i = ty; i < 32; i += 8)
        Wt[(size_t)(n0 + i) * K + k0 + tx] = (__bf16)tile[tx][i];
}

// ---------------- GEMM: C[M][N] = A[M][K] @ Bt[N][K]^T  (bf16 in, fp32 acc) ---------
// epi==0: Cf[row][col] = acc + bias[col]          (fp32 out)
// epi==1: split into Q/K/V bf16 tensors [B][H][S][D], + bias
__global__ __launch_bounds__(256) void gemm_bt(const __bf16* __restrict__ A,
                                               const __bf16* __restrict__ Bt,
                                               const float* __restrict__ bias,
                                               float* __restrict__ Cf,
                                               __bf16* __restrict__ Cq,
                                               __bf16* __restrict__ Ck,
                                               __bf16* __restrict__ Cv,
                                               int M, int N, int K, int epi) {
    __shared__ __align__(16) __bf16 As[128 * 40];
    __shared__ __align__(16) __bf16 Bs[128 * 40];

    int nb = N >> 7;
    int bx = blockIdx.x % nb;
    int by = blockIdx.x / nb;
    int row0 = by * 128, col0 = bx * 128;

    int tid = threadIdx.x;
    int wave = tid >> 6, lane = tid & 63;
    int quad = lane >> 4, lrow = lane & 15;
    int wm = wave >> 1, wn = wave & 1;

    int r1 = tid >> 2;
    int kk = (tid & 3) * 8;
    const __bf16* Aptr = A + (size_t)(row0 + r1) * K + kk;
    const __bf16* Bptr = Bt + (size_t)(col0 + r1) * K + kk;

    f32x4 acc[4][4];
    f32x4 zero = {0.f, 0.f, 0.f, 0.f};
    #pragma unroll
    for (int i = 0; i < 4; i++)
        #pragma unroll
        for (int j = 0; j < 4; j++) acc[i][j] = zero;

    for (int k0 = 0; k0 < K; k0 += 32) {
        bf16x8 a0 = *reinterpret_cast<const bf16x8*>(Aptr + k0);
        bf16x8 a1 = *reinterpret_cast<const bf16x8*>(Aptr + (size_t)64 * K + k0);
        bf16x8 b0 = *reinterpret_cast<const bf16x8*>(Bptr + k0);
        bf16x8 b1 = *reinterpret_cast<const bf16x8*>(Bptr + (size_t)64 * K + k0);
        __syncthreads();
        *reinterpret_cast<bf16x8*>(&As[r1 * 40 + kk]) = a0;
        *reinterpret_cast<bf16x8*>(&As[(r1 + 64) * 40 + kk]) = a1;
        *reinterpret_cast<bf16x8*>(&Bs[r1 * 40 + kk]) = b0;
        *reinterpret_cast<bf16x8*>(&Bs[(r1 + 64) * 40 + kk]) = b1;
        __syncthreads();

        bf16x8 af[4], bfr[4];
        #pragma unroll
        for (int i = 0; i < 4; i++)
            af[i] = *reinterpret_cast<const bf16x8*>(&As[(wm * 64 + i * 16 + lrow) * 40 + quad * 8]);
        #pragma unroll
        for (int j = 0; j < 4; j++)
            bfr[j] = *reinterpret_cast<const bf16x8*>(&Bs[(wn * 64 + j * 16 + lrow) * 40 + quad * 8]);
        #pragma unroll
        for (int i = 0; i < 4; i++)
            #pragma unroll
            for (int j = 0; j < 4; j++)
                acc[i][j] = __builtin_amdgcn_mfma_f32_16x16x32_bf16(af[i], bfr[j], acc[i][j], 0, 0, 0);
    }

    // epilogue: D row = quad*4 + reg, col = lrow within each 16x16 tile
    #pragma unroll
    for (int i = 0; i < 4; i++) {
        int rowb = row0 + wm * 64 + i * 16 + quad * 4;
        #pragma unroll
        for (int j = 0; j < 4; j++) {
            int col = col0 + wn * 64 + j * 16 + lrow;
            float bsv = bias[col];
            #pragma unroll
            for (int r = 0; r < 4; r++) {
                int row = rowb + r;
                float v = acc[i][j][r] + bsv;
                if (epi == 0) {
                    Cf[(size_t)row * N + col] = v;
                } else {
                    int part = col >> 10;
                    int h = (col >> 6) & 15;
                    int d = col & 63;
                    int b = row >> 11;
                    int s = row & 2047;
                    __bf16* dst = (part == 0) ? Cq : ((part == 1) ? Ck : Cv);
                    dst[((size_t)(b * NHEADS + h) * SLEN + s) * HDIM + d] = (__bf16)v;
                }
            }
        }
    }
}

// ---------------- RoPE in place on Q,K  [BH][S][64], pos = s % 256 ----------------
__global__ __launch_bounds__(256) void rope_kernel(__bf16* __restrict__ Q,
                                                   __bf16* __restrict__ K,
                                                   const float* __restrict__ rope) {
    int idx = blockIdx.x * 256 + threadIdx.x;  // [0, 32*2048*32)
    int p = idx & 31;
    int s = (idx >> 5) & 2047;
    int bh = idx >> 16;
    size_t off = ((size_t)bh * SLEN + s) * HDIM + 2 * p;
    int pos = s & 255;
    float c = rope[(pos * 32 + p) * 2];
    float sn = rope[(pos * 32 + p) * 2 + 1];
    float q0 = (float)Q[off], q1 = (float)Q[off + 1];
    Q[off]     = (__bf16)(q0 * c - q1 * sn);
    Q[off + 1] = (__bf16)(q1 * c + q0 * sn);
    float k0 = (float)K[off], k1 = (float)K[off + 1];
    K[off]     = (__bf16)(k0 * c - k1 * sn);
    K[off + 1] = (__bf16)(k1 * c + k0 * sn);
}

// ---------------- windowed flash attention ----------------
// grid: B*H*(S/64) blocks; block = 4 waves; wave handles 16 queries.
__global__ __launch_bounds__(256) void attn_kernel(const __bf16* __restrict__ Q,
                                                   const __bf16* __restrict__ Kt,
                                                   const __bf16* __restrict__ V,
                                                   __bf16* __restrict__ O) {
    __shared__ __align__(16) __bf16 Vt[64][40];       // [d][k] for PV B-operand
    __shared__ __align__(16) __bf16 Pl[4][16][40];    // per-wave P roundtrip

    int qt = blockIdx.x & 31;
    int bh = blockIdx.x >> 5;
    int q0 = qt * 64;
    const __bf16* Qbh = Q + (size_t)bh * SLEN * HDIM;
    const __bf16* Kbh = Kt + (size_t)bh * SLEN * HDIM;
    const __bf16* Vbh = V + (size_t)bh * SLEN * HDIM;

    int tid = threadIdx.x;
    int wave = tid >> 6, lane = tid & 63;
    int quad = lane >> 4, lrow = lane & 15;
    int wq0 = q0 + wave * 16;

    // Q fragments (A-operand): lane holds Q[lrow][quad*8 + j] (+32 for second half)
    bf16x8 qa0 = *reinterpret_cast<const bf16x8*>(Qbh + (size_t)(wq0 + lrow) * HDIM + quad * 8);
    bf16x8 qa1 = *reinterpret_cast<const bf16x8*>(Qbh + (size_t)(wq0 + lrow) * HDIM + 32 + quad * 8);

    f32x4 zero = {0.f, 0.f, 0.f, 0.f};
    f32x4 acc[4];
    #pragma unroll
    for (int t = 0; t < 4; t++) acc[t] = zero;
    float m_i[4], l_i[4];
    #pragma unroll
    for (int r = 0; r < 4; r++) { m_i[r] = -1e30f; l_i[r] = 0.f; }

    int kstart = q0 - 128; if (kstart < 0) kstart = 0;
    int kend = q0 + 63 + 128 + 1; if (kend > SLEN) kend = SLEN;

    for (int kc = kstart; kc < kend; kc += 32) {
        __syncthreads();
        // stage V chunk transposed: Vt[d][k], 32 keys x 64 dims
        {
            int keyl = tid >> 3;
            int db = (tid & 7) * 8;
            bf16x8 vv = *reinterpret_cast<const bf16x8*>(Vbh + (size_t)(kc + keyl) * HDIM + db);
            #pragma unroll
            for (int i = 0; i < 8; i++) Vt[db + i][keyl] = vv[i];
        }
        __syncthreads();

        // QK^T for two 16-key subtiles
        f32x4 c0 = zero, c1 = zero;
        {
            const __bf16* krow0 = Kbh + (size_t)(kc + lrow) * HDIM;
            const __bf16* krow1 = Kbh + (size_t)(kc + 16 + lrow) * HDIM;
            bf16x8 kb0a = *reinterpret_cast<const bf16x8*>(krow0 + quad * 8);
            bf16x8 kb0b = *reinterpret_cast<const bf16x8*>(krow0 + 32 + quad * 8);
            bf16x8 kb1a = *reinterpret_cast<const bf16x8*>(krow1 + quad * 8);
            bf16x8 kb1b = *reinterpret_cast<const bf16x8*>(krow1 + 32 + quad * 8);
            c0 = __builtin_amdgcn_mfma_f32_16x16x32_bf16(qa0, kb0a, c0, 0, 0, 0);
            c0 = __builtin_amdgcn_mfma_f32_16x16x32_bf16(qa1, kb0b, c0, 0, 0, 0);
            c1 = __builtin_amdgcn_mfma_f32_16x16x32_bf16(qa0, kb1a, c1, 0, 0, 0);
            c1 = __builtin_amdgcn_mfma_f32_16x16x32_bf16(qa1, kb1b, c1, 0, 0, 0);
        }

        // online softmax per query row (row = quad*4 + r lives in this quad's 16 lanes)
        #pragma unroll
        for (int r = 0; r < 4; r++) {
            int q = wq0 + quad * 4 + r;
            int key0 = kc + lrow;
            int key1 = kc + 16 + lrow;
            bool v0 = (key0 >= q - 128) && (key0 <= q + 128);
            bool v1 = (key1 >= q - 128) && (key1 <= q + 128);
            float s0 = v0 ? c0[r] * 0.125f : -1e30f;
            float s1 = v1 ? c1[r] * 0.125f : -1e30f;
            float rm = fmaxf(s0, s1);
            #pragma unroll
            for (int off = 1; off < 16; off <<= 1) rm = fmaxf(rm, __shfl_xor(rm, off, 64));
            float mnew = fmaxf(m_i[r], rm);
            float alpha = __expf(m_i[r] - mnew);
            float p0 = v0 ? __expf(s0 - mnew) : 0.0f;
            float p1 = v1 ? __expf(s1 - mnew) : 0.0f;
            float rs = p0 + p1;
            #pragma unroll
            for (int off = 1; off < 16; off <<= 1) rs += __shfl_xor(rs, off, 64);
            l_i[r] = l_i[r] * alpha + rs;
            m_i[r] = mnew;
            #pragma unroll
            for (int t = 0; t < 4; t++) acc[t][r] *= alpha;
            Pl[wave][quad * 4 + r][lrow] = (__bf16)p0;
            Pl[wave][quad * 4 + r][16 + lrow] = (__bf16)p1;
        }
        // wave-local LDS roundtrip: ensure P writes complete before frag reads
        asm volatile("s_waitcnt lgkmcnt(0)" ::: "memory");

        // P A-fragment: lane holds P[lrow][quad*8 + j]
        bf16x8 ap = *reinterpret_cast<const bf16x8*>(&Pl[wave][lrow][quad * 8]);
        #pragma unroll
        for (int t = 0; t < 4; t++) {
            bf16x8 bv = *reinterpret_cast<const bf16x8*>(&Vt[t * 16 + lrow][quad * 8]);
            acc[t] = __builtin_amdgcn_mfma_f32_16x16x32_bf16(ap, bv, acc[t], 0, 0, 0);
        }
    }

    // epilogue: O[q][d] = acc / l ; write bf16 [B][S][H*D]
    int b = bh >> 4, h = bh & 15;
    #pragma unroll
    for (int r = 0; r < 4; r++) {
        int stok = q0 + wave * 16 + quad * 4 + r;
        float inv = 1.0f / l_i[r];
        size_t base = ((size_t)b * SLEN + stok) * 1024 + h * HDIM;
        #pragma unroll
        for (int t = 0; t < 4; t++) {
            O[base + t * 16 + lrow] = (__bf16)(acc[t][r] * inv);
        }
    }
}

extern "C" void kernel_launch(void* const* d_in, const int* in_sizes, int n_in,
                              void* d_out, int out_size, void* d_ws, size_t ws_size,
                              hipStream_t stream) {
    const float* hidden = (const float*)d_in[0];   // [2,2048,1024]
    const float* Wqkv   = (const float*)d_in[1];   // [1024,3072]
    const float* bqkv   = (const float*)d_in[2];   // [3072]
    const float* Wo     = (const float*)d_in[3];   // [1024,1024]
    const float* bo     = (const float*)d_in[4];   // [1024]
    const float* rope   = (const float*)d_in[5];   // [256,32,2]
    float* out = (float*)d_out;                    // [2,2048,1024] fp32

    char* ws = (char*)d_ws;
    __bf16* A1  = (__bf16*)(ws);                   //  8 MiB: hidden bf16 [4096][1024]
    __bf16* Wt  = (__bf16*)(ws + 8388608);         //  6 MiB: Wqkv^T bf16 [3072][1024]
    __bf16* Wot = (__bf16*)(ws + 14680064);        //  2 MiB: Wo^T bf16 [1024][1024]
    __bf16* Qb  = (__bf16*)(ws + 16777216);        //  8 MiB: Q [B][H][S][64]
    __bf16* Kb  = (__bf16*)(ws + 25165824);        //  8 MiB: K
    __bf16* Vb  = (__bf16*)(ws + 33554432);        //  8 MiB: V
    __bf16* AO  = (__bf16*)(ws + 41943040);        //  8 MiB: attn out [4096][1024]

    cast_f32_bf16<<<4096, 256, 0, stream>>>(hidden, A1, 1048576);
    transpose_cast<<<dim3(96, 32), dim3(32, 8), 0, stream>>>(Wqkv, Wt, 1024, 3072);
    transpose_cast<<<dim3(32, 32), dim3(32, 8), 0, stream>>>(Wo, Wot, 1024, 1024);

    // QKV projection: [4096,1024] @ [1024,3072] -> split Q/K/V [B][H][S][64] bf16
    gemm_bt<<<32 * 24, 256, 0, stream>>>(A1, Wt, bqkv, nullptr, Qb, Kb, Vb,
                                         4096, 3072, 1024, 1);
    // RoPE on Q,K in place
    rope_kernel<<<8192, 256, 0, stream>>>(Qb, Kb, rope);
    // windowed attention -> AO [4096][1024] bf16
    attn_kernel<<<2 * 16 * 32, 256, 0, stream>>>(Qb, Kb, Vb, AO);
    // output projection: [4096,1024] @ [1024,1024] + bias -> d_out fp32
    gemm_bt<<<32 * 8, 256, 0, stream>>>(AO, Wot, bo, out, nullptr, nullptr, nullptr,
                                        4096, 1024, 1024, 0);
}